// Round 5
// baseline (295.132 us; speedup 1.0000x reference)
//
#include <hip/hip_runtime.h>

#define B_ 4
#define C_ 16
#define L_ 512
#define H_ 1024
// rows per half = B*C*L = 32768 = 2^15

typedef float f4 __attribute__((ext_vector_type(4)));

// Kernel 1: one wave per 4 consecutive rows of ONE half. All 16 row-loads
// issued BEFORE a sched_barrier(0) fence (16 KB/wave in flight), CACHED loads
// (the harness's d_in restore leaves ~half the input L2/L3-resident — round-2
// FETCH_SIZE showed 134 MB of 256 MB), then FMA + 64-lane butterfly reduce,
// transposed scatter. se layout: se[half][b][l][c].
__global__ __launch_bounds__(256) void dot_kernel(const f4* __restrict__ start,
                                                  const f4* __restrict__ endp,
                                                  const f4* __restrict__ v,
                                                  float* __restrict__ se) {
    const int lane = threadIdx.x & 63;
    const int wv   = (blockIdx.x << 2) | (threadIdx.x >> 6);   // 0..16383
    const int half = wv >> 13;                                 // 8192 waves/half
    const int r0   = (wv & 8191) << 2;                         // 4 rows per wave

    const f4* __restrict__ base = half ? endp : start;         // scalar select
    const f4* __restrict__ vh   = v + half * (H_ / 4);

    f4 vf[4];
#pragma unroll
    for (int k = 0; k < 4; ++k) vf[k] = vh[k * 64 + lane];

    // Issue ALL 16 global loads; fence keeps consumers below:
    // 64 live dest VGPRs = 16-deep MLP per wave.
    const f4* in = base + (size_t)r0 * (H_ / 4);
    f4 x[4][4];
#pragma unroll
    for (int r = 0; r < 4; ++r)
#pragma unroll
        for (int k = 0; k < 4; ++k)
            x[r][k] = in[r * (H_ / 4) + k * 64 + lane];

    __builtin_amdgcn_sched_barrier(0);

    float acc[4];
#pragma unroll
    for (int r = 0; r < 4; ++r) {
        float a = 0.f;
#pragma unroll
        for (int k = 0; k < 4; ++k)
            a += x[r][k].x * vf[k].x + x[r][k].y * vf[k].y +
                 x[r][k].z * vf[k].z + x[r][k].w * vf[k].w;
        acc[r] = a;
    }

#pragma unroll
    for (int m = 32; m > 0; m >>= 1) {
#pragma unroll
        for (int r = 0; r < 4; ++r) acc[r] += __shfl_xor(acc[r], m, 64);
    }

    if (lane == 0) {
        const int b  = r0 >> 13;
        const int c  = (r0 >> 9) & (C_ - 1);
        const int l0 = r0 & (L_ - 1);
        float* p = se + (half << 15) + (((b << 9) | l0) << 4) + c;
#pragma unroll
        for (int r = 0; r < 4; ++r) p[r << 4] = acc[r];
    }
}

// Kernel 2: one block per (b,i). out[b,i,j,c] = s[b,i,c] + e[b,j,c].
// e streams from L2 (se is 256 KB); stores are NONTEMPORAL (write-only output,
// keeps the caches free for next iteration's inputs).
__global__ __launch_bounds__(256) void outer_kernel(const f4* __restrict__ se4,
                                                    f4* __restrict__ out4) {
    const int bi  = blockIdx.x;                // b*L + i
    const int b   = bi >> 9;
    const int tid = threadIdx.x;

    const f4 s = se4[(bi << 2) | (tid & 3)];
    const f4* __restrict__ e = se4 + (B_ * L_ * 4) + (b << 11);
    f4* __restrict__ o = out4 + (size_t)bi * (L_ * C_ / 4);

    f4 ev[8];
#pragma unroll
    for (int it = 0; it < 8; ++it) ev[it] = e[it * 256 + tid];
#pragma unroll
    for (int it = 0; it < 8; ++it) {
        f4 r = s + ev[it];
        __builtin_nontemporal_store(r, o + it * 256 + tid);
    }
}

extern "C" void kernel_launch(void* const* d_in, const int* in_sizes, int n_in,
                              void* d_out, int out_size, void* d_ws, size_t ws_size,
                              hipStream_t stream) {
    const f4* start = (const f4*)d_in[0];
    const f4* endp  = (const f4*)d_in[1];
    const f4* v     = (const f4*)d_in[2];
    float*    se    = (float*)d_ws;      // 2*B*L*C floats = 256 KB
    f4*       out4  = (f4*)d_out;

    dot_kernel<<<4096, 256, 0, stream>>>(start, endp, v, se);
    outer_kernel<<<B_ * L_, 256, 0, stream>>>((const f4*)se, out4);
}